// Round 7
// baseline (142.745 us; speedup 1.0000x reference)
//
#include <hip/hip_runtime.h>
#include <hip/hip_bf16.h>

typedef __attribute__((ext_vector_type(8))) short bf16x8;
typedef __attribute__((ext_vector_type(4))) float f32x4;

// ---------------- ws layout ----------------
// F    : bf16 [32768][672]            @ 0          (44,040,192 B)
// W2   : bf16 [768][672]              @ 44,040,192 (1,032,192 B)
// biasT: f32  [768]                   @ 45,072,384 (3,072 B)
// part : f32  [512]                   @ 45,075,456 (2,048 B)
// dmin : f32  [32]                    @ 45,077,504 (128 B)

__device__ __forceinline__ void async_copy16(const void* gsrc, void* ldst) {
    __builtin_amdgcn_global_load_lds(
        (const __attribute__((address_space(1))) void*)gsrc,
        (__attribute__((address_space(3))) void*)ldst,
        16, 0, 0);
}

__device__ __forceinline__ unsigned short f2bf(float f) {  // RNE, matches __float2bfloat16
    unsigned u = __float_as_uint(f);
    u += 0x7FFFu + ((u >> 16) & 1u);
    return (unsigned short)(u >> 16);
}

// -------- per-batch min (two stage) --------
__global__ __launch_bounds__(256) void min_partial_kernel(const float* __restrict__ x,
                                                          float* __restrict__ partial) {
    const int blk = blockIdx.x;           // 512 blocks: 32 batches x 16 chunks
    const int b = blk >> 4, c = blk & 15;
    const float4* p = (const float4*)(x + (size_t)b * 262144 + (size_t)c * 16384);
    float mn = 3.0e38f;
    for (int i = threadIdx.x; i < 4096; i += 256) {
        float4 v = p[i];
        mn = fminf(mn, fminf(fminf(v.x, v.y), fminf(v.z, v.w)));
    }
    #pragma unroll
    for (int off = 32; off > 0; off >>= 1)
        mn = fminf(mn, __shfl_down(mn, off));
    __shared__ float red[4];
    if ((threadIdx.x & 63) == 0) red[threadIdx.x >> 6] = mn;
    __syncthreads();
    if (threadIdx.x == 0)
        partial[blk] = fminf(fminf(red[0], red[1]), fminf(red[2], red[3]));
}

__global__ void min_final_kernel(const float* __restrict__ partial, float* __restrict__ dmin) {
    const int t = threadIdx.x;
    if (t < 32) {
        float mn = 3.0e38f;
        for (int i = 0; i < 16; ++i) mn = fminf(mn, partial[t * 16 + i]);
        dmin[t] = mn;
    }
}

// -------- weight repack: W2[e][k] bf16, k = [g16 dh|g16 mp|g8 dh|g8 mp|g4 dh|g4 mp] --------
__global__ __launch_bounds__(256) void prep_kernel(const float* __restrict__ w0, const float* __restrict__ b0,
                                                   const float* __restrict__ w1, const float* __restrict__ b1,
                                                   const float* __restrict__ w2, const float* __restrict__ b2,
                                                   __hip_bfloat16* __restrict__ W2, float* __restrict__ biasT) {
    const int idx = blockIdx.x * 256 + threadIdx.x;
    if (idx < 768 * 672) {
        const int e = idx / 672, k = idx - e * 672;
        float v;
        if (k < 512)      v = w0[e * 512 + k];          // (2,16,16) flat
        else if (k < 640) v = w1[e * 128 + (k - 512)];  // (2,8,8) flat
        else              v = w2[e * 32  + (k - 640)];  // (2,4,4) flat
        W2[idx] = __float2bfloat16(v);
    }
    if (idx < 768) biasT[idx] = b0[idx] + b1[idx] + b2[idx];
}

// -------- per-patch: PURE REGISTER, one wave per patch, zero LDS (R6-proven) --------
__global__ __launch_bounds__(256) void patch_kernel(const float* __restrict__ x,
                                                    const float* __restrict__ dmin,
                                                    __hip_bfloat16* __restrict__ F,
                                                    float* __restrict__ maskout) {
    const int t = threadIdx.x;
    const int w = t >> 6, lane = t & 63;
    const int pid = blockIdx.x * 4 + w;       // wave = patch
    const int b = pid >> 10, n = pid & 1023;
    const int gi = n >> 5, gj = n & 31;
    const int row = lane >> 2, cq = lane & 3, cg = cq * 4;
    const float thr = dmin[b] + 1e-6f;

    const float4 v = *(const float4*)(x + ((size_t)(b * 512 + gi * 16 + row)) * 512 + gj * 16 + cg);
    float enc0, enc1, enc2, enc3;
    ushort4 om;
    {
        const bool v0 = v.x > thr, v1 = v.y > thr, v2 = v.z > thr, v3 = v.w > thr;
        enc0 = v0 ? fmaf(v.x, 0.99999000009999f, 256.0f) : 0.0f;   // 256 + d/1.00001
        enc1 = v1 ? fmaf(v.y, 0.99999000009999f, 256.0f) : 0.0f;
        enc2 = v2 ? fmaf(v.z, 0.99999000009999f, 256.0f) : 0.0f;
        enc3 = v3 ? fmaf(v.w, 0.99999000009999f, 256.0f) : 0.0f;
        om.x = v0 ? 0x3F80 : 0; om.y = v1 ? 0x3F80 : 0;            // bf16(1.0/0.0)
        om.z = v2 ? 0x3F80 : 0; om.w = v3 ? 0x3F80 : 0;
    }

    // ---- pools from initial encoded values (register butterflies) ----
    const float vs0 = enc0 + __shfl(enc0, lane ^ 4);   // vertical row-pair sums
    const float vs1 = enc1 + __shfl(enc1, lane ^ 4);
    const float vs2 = enc2 + __shfl(enc2, lane ^ 4);
    const float vs3 = enc3 + __shfl(enc3, lane ^ 4);
    const float a80 = vs0 + vs1, a81 = vs2 + vs3;      // g8 cells (row>>1,2cq),(row>>1,2cq+1)
    const int r8 = lane >> 3, c8 = lane & 7;
    const int src8 = r8 * 8 + (c8 >> 1);
    const float t80 = __shfl(a80, src8), t81 = __shfl(a81, src8);
    const float sum8 = (c8 & 1) ? t81 : t80;           // encoded 2x2 sum of my g8 cell
    const float N8 = floorf(sum8 * 0.00390625f);
    const float S8 = fmaf(N8, -256.0f, sum8);
    const float mp8 = N8 * 0.25f;
    const float dh8 = (S8 * 0.2500025f) / fmaf(N8, 0.25f, 1e-5f);  // (S/1.00001/4)/(mp8+1e-5)
    float f8v = (N8 >= 1.0f) ? fmaxf(dh8, 0.0f) : -1.0f;
    // g4 sums from g8 sums
    const float vp8 = sum8 + __shfl(sum8, lane ^ 8);
    const float sum4w = vp8 + __shfl(vp8, lane ^ 1);   // g4 cell (r8>>1,c8>>1), duplicated
    const int cell4 = lane & 15;
    const int r4 = cell4 >> 2, c4 = cell4 & 3;
    const float s4 = __shfl(sum4w, r4 * 16 + c4 * 2);
    const float N4 = floorf(s4 * 0.00390625f);
    const float S4 = fmaf(N4, -256.0f, s4);
    const float mp4 = N4 * 0.0625f;
    const float dh4 = (S4 * 0.062500625f) / fmaf(N4, 0.0625f, 1e-5f);
    float f4v = (N4 >= 1.0f) ? fmaxf(dh4, 0.0f) : -1.0f;

    // ---- g16 fill: 4 contiguous cells/lane, 14 shfls/iter, encode arithmetic ----
    {
        const float okT = (row > 0) ? 1.f : 0.f, okB = (row < 15) ? 1.f : 0.f;
        const float okL = (cq > 0) ? 1.f : 0.f, okR = (cq < 3) ? 1.f : 0.f;
        const float okTL = okT * okL, okTR = okT * okR, okBL = okB * okL, okBR = okB * okR;
        const int liU = (lane - 4) & 63, liD = (lane + 4) & 63;
        const int liL = (lane - 1) & 63, liR = (lane + 1) & 63;
        const int liUL = (lane - 5) & 63, liUR = (lane - 3) & 63;
        const int liDL = (lane + 3) & 63, liDR = (lane + 5) & 63;
        for (;;) {
            float u0 = __shfl(enc0, liU), u1 = __shfl(enc1, liU);
            float u2 = __shfl(enc2, liU), u3 = __shfl(enc3, liU);
            float b0_ = __shfl(enc0, liD), b1_ = __shfl(enc1, liD);
            float b2_ = __shfl(enc2, liD), b3_ = __shfl(enc3, liD);
            float eL  = __shfl(enc3, liL)  * okL;
            float eR  = __shfl(enc0, liR)  * okR;
            float eUL = __shfl(enc3, liUL) * okTL;
            float eUR = __shfl(enc0, liUR) * okTR;
            float eDL = __shfl(enc3, liDL) * okBL;
            float eDR = __shfl(enc0, liDR) * okBR;
            u0 *= okT; u1 *= okT; u2 *= okT; u3 *= okT;
            b0_ *= okB; b1_ *= okB; b2_ *= okB; b3_ *= okB;
            const float c0 = eUL + eL + eDL;
            const float c1 = u0 + enc0 + b0_;
            const float c2 = u1 + enc1 + b1_;
            const float c3 = u2 + enc2 + b2_;
            const float c4_ = u3 + enc3 + b3_;
            const float c5 = eUR + eR + eDR;
            float w0s = c0 + c1 + c2, w1s = c1 + c2 + c3;
            float w2s = c2 + c3 + c4_, w3s = c3 + c4_ + c5;
            asm volatile("" :: "v"(w0s), "v"(w1s), "v"(w2s), "v"(w3s));  // pin (uniform path)
            int fill = 0;
            if (enc0 < 256.f) {
                const float Nf = floorf(w0s * 0.00390625f);
                if (Nf >= 1.f) { enc0 = 256.f + fmaxf(fmaf(Nf, -256.f, w0s), 0.f) * __builtin_amdgcn_rcpf(Nf); fill = 1; }
            }
            if (enc1 < 256.f) {
                const float Nf = floorf(w1s * 0.00390625f);
                if (Nf >= 1.f) { enc1 = 256.f + fmaxf(fmaf(Nf, -256.f, w1s), 0.f) * __builtin_amdgcn_rcpf(Nf); fill = 1; }
            }
            if (enc2 < 256.f) {
                const float Nf = floorf(w2s * 0.00390625f);
                if (Nf >= 1.f) { enc2 = 256.f + fmaxf(fmaf(Nf, -256.f, w2s), 0.f) * __builtin_amdgcn_rcpf(Nf); fill = 1; }
            }
            if (enc3 < 256.f) {
                const float Nf = floorf(w3s * 0.00390625f);
                if (Nf >= 1.f) { enc3 = 256.f + fmaxf(fmaf(Nf, -256.f, w3s), 0.f) * __builtin_amdgcn_rcpf(Nf); fill = 1; }
            }
            if (!__any(fill)) break;
        }
    }
    unsigned short* Fp = (unsigned short*)(F + (size_t)pid * 672);
    {
        ushort4 o;
        o.x = f2bf(fmaxf(enc0 - 256.f, 0.f)); o.y = f2bf(fmaxf(enc1 - 256.f, 0.f));
        o.z = f2bf(fmaxf(enc2 - 256.f, 0.f)); o.w = f2bf(fmaxf(enc3 - 256.f, 0.f));
        const int co = row * 16 + cg;
        *(ushort4*)(Fp + co) = o;
        *(ushort4*)(Fp + 256 + co) = om;
    }

    // ---- g8 fill (unconditional shfl + post-masks) ----
    {
        const float okU = (r8 > 0) ? 1.f : 0.f;
        const float okD = (r8 < 7) ? 1.f : 0.f;
        const float okL = (c8 > 0) ? 1.f : 0.f;
        const float okR = (c8 < 7) ? 1.f : 0.f;
        for (int it = 0; it < 8; ++it) {
            const float nU  = __shfl(f8v, (lane - 8) & 63);
            const float nD  = __shfl(f8v, (lane + 8) & 63);
            const float nL  = __shfl(f8v, (lane - 1) & 63);
            const float nR  = __shfl(f8v, (lane + 1) & 63);
            const float nUL = __shfl(f8v, (lane - 9) & 63);
            const float nUR = __shfl(f8v, (lane - 7) & 63);
            const float nDL = __shfl(f8v, (lane + 7) & 63);
            const float nDR = __shfl(f8v, (lane + 9) & 63);
            const float S = okU * fmaxf(nU, 0.f) + okD * fmaxf(nD, 0.f)
                          + okL * fmaxf(nL, 0.f) + okR * fmaxf(nR, 0.f)
                          + (okU * okL) * fmaxf(nUL, 0.f) + (okU * okR) * fmaxf(nUR, 0.f)
                          + (okD * okL) * fmaxf(nDL, 0.f) + (okD * okR) * fmaxf(nDR, 0.f);
            const float N = okU * ((nU >= 0.f) ? 1.f : 0.f) + okD * ((nD >= 0.f) ? 1.f : 0.f)
                          + okL * ((nL >= 0.f) ? 1.f : 0.f) + okR * ((nR >= 0.f) ? 1.f : 0.f)
                          + (okU * okL) * ((nUL >= 0.f) ? 1.f : 0.f) + (okU * okR) * ((nUR >= 0.f) ? 1.f : 0.f)
                          + (okD * okL) * ((nDL >= 0.f) ? 1.f : 0.f) + (okD * okR) * ((nDR >= 0.f) ? 1.f : 0.f);
            asm volatile("" :: "v"(S), "v"(N));   // pin to uniform path
            int fill = 0; float nv = 0.f;
            if (f8v < 0.f && N > 0.f) { nv = S / N; fill = 1; }
            const bool any = __any(fill);
            if (fill) f8v = nv;
            if (!any) break;
        }
        Fp[512 + lane] = f2bf(fmaxf(f8v, 0.f));
        Fp[576 + lane] = f2bf(mp8);
    }

    // ---- g4 fill (4x4 mirrored across lane groups) ----
    {
        const float okU = (r4 > 0) ? 1.f : 0.f;
        const float okD = (r4 < 3) ? 1.f : 0.f;
        const float okL = (c4 > 0) ? 1.f : 0.f;
        const float okR = (c4 < 3) ? 1.f : 0.f;
        for (int it = 0; it < 4; ++it) {
            const float nU  = __shfl(f4v, (cell4 - 4) & 63);
            const float nD  = __shfl(f4v, (cell4 + 4) & 63);
            const float nL  = __shfl(f4v, (cell4 - 1) & 63);
            const float nR  = __shfl(f4v, (cell4 + 1) & 63);
            const float nUL = __shfl(f4v, (cell4 - 5) & 63);
            const float nUR = __shfl(f4v, (cell4 - 3) & 63);
            const float nDL = __shfl(f4v, (cell4 + 3) & 63);
            const float nDR = __shfl(f4v, (cell4 + 5) & 63);
            const float S = okU * fmaxf(nU, 0.f) + okD * fmaxf(nD, 0.f)
                          + okL * fmaxf(nL, 0.f) + okR * fmaxf(nR, 0.f)
                          + (okU * okL) * fmaxf(nUL, 0.f) + (okU * okR) * fmaxf(nUR, 0.f)
                          + (okD * okL) * fmaxf(nDL, 0.f) + (okD * okR) * fmaxf(nDR, 0.f);
            const float N = okU * ((nU >= 0.f) ? 1.f : 0.f) + okD * ((nD >= 0.f) ? 1.f : 0.f)
                          + okL * ((nL >= 0.f) ? 1.f : 0.f) + okR * ((nR >= 0.f) ? 1.f : 0.f)
                          + (okU * okL) * ((nUL >= 0.f) ? 1.f : 0.f) + (okU * okR) * ((nUR >= 0.f) ? 1.f : 0.f)
                          + (okD * okL) * ((nDL >= 0.f) ? 1.f : 0.f) + (okD * okR) * ((nDR >= 0.f) ? 1.f : 0.f);
            asm volatile("" :: "v"(S), "v"(N));   // pin to uniform path
            int fill = 0; float nv = 0.f;
            if (f4v < 0.f && N > 0.f) { nv = S / N; fill = 1; }
            const bool any = __any(fill);
            if (fill) f4v = nv;
            if (!any) break;
        }
        if (lane < 16) {
            Fp[640 + lane] = f2bf(fmaxf(f4v, 0.f));
            Fp[656 + lane] = f2bf(mp4);
        }
        const unsigned long long bal = __ballot(lane < 16 && N4 >= 1.0f);
        if (lane == 0) maskout[pid] = bal ? 1.0f : 0.0f;
    }
}

// -------- GEMM: out[32768][768] = F[32768][672] @ W2[768][672]^T + biasT --------
// 128x128 tile, BK=32, XCD swizzle, 2-PHASE PIPELINE (T3-minimum):
// double-buffered LDS; next tile's global_load_lds issued BEFORE computing
// the current tile; raw s_barrier + counted vmcnt(4) keeps the 4 in-flight
// next-tile loads pending across the barrier (no vmcnt(0) drain per K-step).
__global__ __launch_bounds__(256) void gemm_kernel(const short* __restrict__ F,
                                                   const short* __restrict__ W2,
                                                   const float* __restrict__ biasT,
                                                   float* __restrict__ out) {
    constexpr int K = 672, N = 768;
    const int bid = blockIdx.x;                    // 1536 = 256 m-tiles x 6 n-tiles
    const int swz = (bid & 7) * 192 + (bid >> 3);  // bijective (1536 % 8 == 0)
    const int tm = swz / 6, tn = swz % 6;
    const int m0 = tm * 128, e0 = tn * 128;
    const int t = threadIdx.x;
    const int wave = t >> 6, lane = t & 63;
    const int wm = wave >> 1, wn = wave & 1;
    const int lg = lane & 15, kc = lane >> 4;

    __shared__ short lds_a[2][4096];   // [buf][kcc(4)][row(128)][8]
    __shared__ short lds_b[2][4096];

    const int s0 = wave * 2, s1 = wave * 2 + 1;
    const int rowA0 = ((s0 & 1) << 6) + lane, kccA0 = s0 >> 1;
    const int rowA1 = ((s1 & 1) << 6) + lane, kccA1 = s1 >> 1;

    f32x4 acc[4][4];
    const f32x4 zero = {0.f, 0.f, 0.f, 0.f};
    #pragma unroll
    for (int i = 0; i < 4; ++i)
        #pragma unroll
        for (int j = 0; j < 4; ++j) acc[i][j] = zero;

    // prologue: stage tile 0 into buf 0
    async_copy16(F  + (size_t)(m0 + rowA0) * K + 0 + kccA0 * 8, &lds_a[0][s0 * 512]);
    async_copy16(W2 + (size_t)(e0 + rowA0) * K + 0 + kccA0 * 8, &lds_b[0][s0 * 512]);
    async_copy16(F  + (size_t)(m0 + rowA1) * K + 0 + kccA1 * 8, &lds_a[0][s1 * 512]);
    async_copy16(W2 + (size_t)(e0 + rowA1) * K + 0 + kccA1 * 8, &lds_b[0][s1 * 512]);

    for (int ki = 0; ki < 21; ++ki) {
        const int cur = ki & 1;
        if (ki < 20) {   // issue next tile into the other buffer (stays in flight)
            const int kb = (ki + 1) * 32;
            async_copy16(F  + (size_t)(m0 + rowA0) * K + kb + kccA0 * 8, &lds_a[cur ^ 1][s0 * 512]);
            async_copy16(W2 + (size_t)(e0 + rowA0) * K + kb + kccA0 * 8, &lds_b[cur ^ 1][s0 * 512]);
            async_copy16(F  + (size_t)(m0 + rowA1) * K + kb + kccA1 * 8, &lds_a[cur ^ 1][s1 * 512]);
            async_copy16(W2 + (size_t)(e0 + rowA1) * K + kb + kccA1 * 8, &lds_b[cur ^ 1][s1 * 512]);
            asm volatile("s_waitcnt vmcnt(4)" ::: "memory");  // tile-ki loads done; next 4 in flight
        } else {
            asm volatile("s_waitcnt vmcnt(0)" ::: "memory");  // last tile: drain
        }
        __builtin_amdgcn_s_barrier();       // all waves' tile-ki data visible
        asm volatile("" ::: "memory");

        bf16x8 af[4], bfr[4];
        #pragma unroll
        for (int i = 0; i < 4; ++i) {
            af[i]  = *(const bf16x8*)&lds_a[cur][(kc * 128 + wm * 64 + i * 16 + lg) * 8];
            bfr[i] = *(const bf16x8*)&lds_b[cur][(kc * 128 + wn * 64 + i * 16 + lg) * 8];
        }
        #pragma unroll
        for (int i = 0; i < 4; ++i)
            #pragma unroll
            for (int j = 0; j < 4; ++j)
                acc[i][j] = __builtin_amdgcn_mfma_f32_16x16x32_bf16(af[i], bfr[j], acc[i][j], 0, 0, 0);

        asm volatile("" ::: "memory");
        __builtin_amdgcn_s_barrier();       // reads done before buf[cur] is re-staged
    }

    // epilogue: C/D layout col=lane&15, row=(lane>>4)*4+reg (m89-verified)
    const int rbase = (lane >> 4) * 4;
    #pragma unroll
    for (int j = 0; j < 4; ++j) {
        const int e = e0 + wn * 64 + j * 16 + lg;
        const float bs = biasT[e];
        #pragma unroll
        for (int i = 0; i < 4; ++i) {
            const int mr = m0 + wm * 64 + i * 16 + rbase;
            #pragma unroll
            for (int r = 0; r < 4; ++r)
                out[(size_t)(mr + r) * N + e] = acc[i][j][r] + bs;
        }
    }
}

extern "C" void kernel_launch(void* const* d_in, const int* in_sizes, int n_in,
                              void* d_out, int out_size, void* d_ws, size_t ws_size,
                              hipStream_t stream) {
    const float* x  = (const float*)d_in[0];
    const float* w0 = (const float*)d_in[1];
    const float* b0 = (const float*)d_in[2];
    const float* w1 = (const float*)d_in[3];
    const float* b1 = (const float*)d_in[4];
    const float* w2 = (const float*)d_in[5];
    const float* b2 = (const float*)d_in[6];
    float* out = (float*)d_out;

    char* ws = (char*)d_ws;
    __hip_bfloat16* F   = (__hip_bfloat16*)ws;
    __hip_bfloat16* W2  = (__hip_bfloat16*)(ws + 44040192);
    float* biasT        = (float*)(ws + 45072384);
    float* partial      = (float*)(ws + 45075456);
    float* dmin         = (float*)(ws + 45077504);
    float* maskout      = out + 25165824;   // feat is 32*1024*768

    min_partial_kernel<<<512, 256, 0, stream>>>(x, partial);
    min_final_kernel<<<1, 64, 0, stream>>>(partial, dmin);
    prep_kernel<<<2016, 256, 0, stream>>>(w0, b0, w1, b1, w2, b2, W2, biasT);
    patch_kernel<<<8192, 256, 0, stream>>>(x, dmin, F, maskout);
    gemm_kernel<<<1536, 256, 0, stream>>>((const short*)F, (const short*)W2, biasT, out);
}

// Round 8
// 141.550 us; speedup vs baseline: 1.0084x; 1.0084x over previous
//
#include <hip/hip_runtime.h>
#include <hip/hip_bf16.h>

typedef __attribute__((ext_vector_type(8))) short bf16x8;
typedef __attribute__((ext_vector_type(4))) float f32x4;

// ---------------- ws layout ----------------
// F    : bf16 [32768][672]            @ 0          (44,040,192 B)
// W2   : bf16 [768][672]              @ 44,040,192 (1,032,192 B)
// biasT: f32  [768]                   @ 45,072,384 (3,072 B)
// part : f32  [512]                   @ 45,075,456 (2,048 B)
// dmin : f32  [32]                    @ 45,077,504 (128 B)

__device__ __forceinline__ void async_copy16(const void* gsrc, void* ldst) {
    __builtin_amdgcn_global_load_lds(
        (const __attribute__((address_space(1))) void*)gsrc,
        (__attribute__((address_space(3))) void*)ldst,
        16, 0, 0);
}

__device__ __forceinline__ unsigned short f2bf(float f) {  // RNE, matches __float2bfloat16
    unsigned u = __float_as_uint(f);
    u += 0x7FFFu + ((u >> 16) & 1u);
    return (unsigned short)(u >> 16);
}

// -------- per-batch min (two stage) --------
__global__ __launch_bounds__(256) void min_partial_kernel(const float* __restrict__ x,
                                                          float* __restrict__ partial) {
    const int blk = blockIdx.x;           // 512 blocks: 32 batches x 16 chunks
    const int b = blk >> 4, c = blk & 15;
    const float4* p = (const float4*)(x + (size_t)b * 262144 + (size_t)c * 16384);
    float mn = 3.0e38f;
    for (int i = threadIdx.x; i < 4096; i += 256) {
        float4 v = p[i];
        mn = fminf(mn, fminf(fminf(v.x, v.y), fminf(v.z, v.w)));
    }
    #pragma unroll
    for (int off = 32; off > 0; off >>= 1)
        mn = fminf(mn, __shfl_down(mn, off));
    __shared__ float red[4];
    if ((threadIdx.x & 63) == 0) red[threadIdx.x >> 6] = mn;
    __syncthreads();
    if (threadIdx.x == 0)
        partial[blk] = fminf(fminf(red[0], red[1]), fminf(red[2], red[3]));
}

__global__ void min_final_kernel(const float* __restrict__ partial, float* __restrict__ dmin) {
    const int t = threadIdx.x;
    if (t < 32) {
        float mn = 3.0e38f;
        for (int i = 0; i < 16; ++i) mn = fminf(mn, partial[t * 16 + i]);
        dmin[t] = mn;
    }
}

// -------- weight repack: W2[e][k] bf16, k = [g16 dh|g16 mp|g8 dh|g8 mp|g4 dh|g4 mp] --------
__global__ __launch_bounds__(256) void prep_kernel(const float* __restrict__ w0, const float* __restrict__ b0,
                                                   const float* __restrict__ w1, const float* __restrict__ b1,
                                                   const float* __restrict__ w2, const float* __restrict__ b2,
                                                   __hip_bfloat16* __restrict__ W2, float* __restrict__ biasT) {
    const int idx = blockIdx.x * 256 + threadIdx.x;
    if (idx < 768 * 672) {
        const int e = idx / 672, k = idx - e * 672;
        float v;
        if (k < 512)      v = w0[e * 512 + k];          // (2,16,16) flat
        else if (k < 640) v = w1[e * 128 + (k - 512)];  // (2,8,8) flat
        else              v = w2[e * 32  + (k - 640)];  // (2,4,4) flat
        W2[idx] = __float2bfloat16(v);
    }
    if (idx < 768) biasT[idx] = b0[idx] + b1[idx] + b2[idx];
}

// -------- per-patch: PURE REGISTER, one wave per patch, zero LDS --------
// All three grids use the encode trick: valid -> 256 + dh, invalid -> 0.
// Masked 3x3 window sum s: N = floor(s/256), S = s - 256N, fill = 256 + S/N.
// ALL __shfl unconditional (masked index), 0/1 masks applied AFTER the
// shuffle, asm-pin keeps them on the uniform path (R3/R4 EXEC-mask bug fix).
__global__ __launch_bounds__(256) void patch_kernel(const float* __restrict__ x,
                                                    const float* __restrict__ dmin,
                                                    __hip_bfloat16* __restrict__ F,
                                                    float* __restrict__ maskout) {
    const int t = threadIdx.x;
    const int w = t >> 6, lane = t & 63;
    const int pid = blockIdx.x * 4 + w;       // wave = patch
    const int b = pid >> 10, n = pid & 1023;
    const int gi = n >> 5, gj = n & 31;
    const int row = lane >> 2, cq = lane & 3, cg = cq * 4;
    const float thr = dmin[b] + 1e-6f;

    const float4 v = *(const float4*)(x + ((size_t)(b * 512 + gi * 16 + row)) * 512 + gj * 16 + cg);
    float enc0, enc1, enc2, enc3;
    ushort4 om;
    {
        const bool v0 = v.x > thr, v1 = v.y > thr, v2 = v.z > thr, v3 = v.w > thr;
        enc0 = v0 ? fmaf(v.x, 0.99999000009999f, 256.0f) : 0.0f;   // 256 + d/1.00001
        enc1 = v1 ? fmaf(v.y, 0.99999000009999f, 256.0f) : 0.0f;
        enc2 = v2 ? fmaf(v.z, 0.99999000009999f, 256.0f) : 0.0f;
        enc3 = v3 ? fmaf(v.w, 0.99999000009999f, 256.0f) : 0.0f;
        om.x = v0 ? 0x3F80 : 0; om.y = v1 ? 0x3F80 : 0;            // bf16(1.0/0.0)
        om.z = v2 ? 0x3F80 : 0; om.w = v3 ? 0x3F80 : 0;
    }

    // ---- pools from initial encoded values (register butterflies) ----
    const float vs0 = enc0 + __shfl(enc0, lane ^ 4);   // vertical row-pair sums
    const float vs1 = enc1 + __shfl(enc1, lane ^ 4);
    const float vs2 = enc2 + __shfl(enc2, lane ^ 4);
    const float vs3 = enc3 + __shfl(enc3, lane ^ 4);
    const float a80 = vs0 + vs1, a81 = vs2 + vs3;      // g8 cells (row>>1,2cq),(row>>1,2cq+1)
    const int r8 = lane >> 3, c8 = lane & 7;
    const int src8 = r8 * 8 + (c8 >> 1);
    const float t80 = __shfl(a80, src8), t81 = __shfl(a81, src8);
    const float sum8 = (c8 & 1) ? t81 : t80;           // encoded 2x2 sum of my g8 cell
    const float N8 = floorf(sum8 * 0.00390625f);
    const float S8 = fmaf(N8, -256.0f, sum8);
    const float mp8 = N8 * 0.25f;
    const float dh8 = (S8 * 0.2500025f) / fmaf(N8, 0.25f, 1e-5f);  // (S/1.00001/4)/(mp8+1e-5)
    float enc8 = (N8 >= 1.0f) ? (256.0f + fmaxf(dh8, 0.0f)) : 0.0f;
    // g4 sums from g8 sums
    const float vp8 = sum8 + __shfl(sum8, lane ^ 8);
    const float sum4w = vp8 + __shfl(vp8, lane ^ 1);   // g4 cell (r8>>1,c8>>1), duplicated
    const int cell4 = lane & 15;
    const int r4 = cell4 >> 2, c4 = cell4 & 3;
    const float s4 = __shfl(sum4w, r4 * 16 + c4 * 2);
    const float N4 = floorf(s4 * 0.00390625f);
    const float S4 = fmaf(N4, -256.0f, s4);
    const float mp4 = N4 * 0.0625f;
    const float dh4 = (S4 * 0.062500625f) / fmaf(N4, 0.0625f, 1e-5f);
    float enc4 = (N4 >= 1.0f) ? (256.0f + fmaxf(dh4, 0.0f)) : 0.0f;

    // ---- g16 fill: 4 contiguous cells/lane, 14 shfls/iter, encode arithmetic ----
    {
        const float okT = (row > 0) ? 1.f : 0.f, okB = (row < 15) ? 1.f : 0.f;
        const float okL = (cq > 0) ? 1.f : 0.f, okR = (cq < 3) ? 1.f : 0.f;
        const float okTL = okT * okL, okTR = okT * okR, okBL = okB * okL, okBR = okB * okR;
        const int liU = (lane - 4) & 63, liD = (lane + 4) & 63;
        const int liL = (lane - 1) & 63, liR = (lane + 1) & 63;
        const int liUL = (lane - 5) & 63, liUR = (lane - 3) & 63;
        const int liDL = (lane + 3) & 63, liDR = (lane + 5) & 63;
        for (;;) {
            float u0 = __shfl(enc0, liU), u1 = __shfl(enc1, liU);
            float u2 = __shfl(enc2, liU), u3 = __shfl(enc3, liU);
            float b0_ = __shfl(enc0, liD), b1_ = __shfl(enc1, liD);
            float b2_ = __shfl(enc2, liD), b3_ = __shfl(enc3, liD);
            float eL  = __shfl(enc3, liL)  * okL;
            float eR  = __shfl(enc0, liR)  * okR;
            float eUL = __shfl(enc3, liUL) * okTL;
            float eUR = __shfl(enc0, liUR) * okTR;
            float eDL = __shfl(enc3, liDL) * okBL;
            float eDR = __shfl(enc0, liDR) * okBR;
            u0 *= okT; u1 *= okT; u2 *= okT; u3 *= okT;
            b0_ *= okB; b1_ *= okB; b2_ *= okB; b3_ *= okB;
            const float c0 = eUL + eL + eDL;
            const float c1 = u0 + enc0 + b0_;
            const float c2 = u1 + enc1 + b1_;
            const float c3 = u2 + enc2 + b2_;
            const float c4_ = u3 + enc3 + b3_;
            const float c5 = eUR + eR + eDR;
            float w0s = c0 + c1 + c2, w1s = c1 + c2 + c3;
            float w2s = c2 + c3 + c4_, w3s = c3 + c4_ + c5;
            asm volatile("" :: "v"(w0s), "v"(w1s), "v"(w2s), "v"(w3s));  // pin (uniform path)
            int fill = 0;
            if (enc0 < 256.f) {
                const float Nf = floorf(w0s * 0.00390625f);
                if (Nf >= 1.f) { enc0 = 256.f + fmaxf(fmaf(Nf, -256.f, w0s), 0.f) * __builtin_amdgcn_rcpf(Nf); fill = 1; }
            }
            if (enc1 < 256.f) {
                const float Nf = floorf(w1s * 0.00390625f);
                if (Nf >= 1.f) { enc1 = 256.f + fmaxf(fmaf(Nf, -256.f, w1s), 0.f) * __builtin_amdgcn_rcpf(Nf); fill = 1; }
            }
            if (enc2 < 256.f) {
                const float Nf = floorf(w2s * 0.00390625f);
                if (Nf >= 1.f) { enc2 = 256.f + fmaxf(fmaf(Nf, -256.f, w2s), 0.f) * __builtin_amdgcn_rcpf(Nf); fill = 1; }
            }
            if (enc3 < 256.f) {
                const float Nf = floorf(w3s * 0.00390625f);
                if (Nf >= 1.f) { enc3 = 256.f + fmaxf(fmaf(Nf, -256.f, w3s), 0.f) * __builtin_amdgcn_rcpf(Nf); fill = 1; }
            }
            if (!__any(fill)) break;
        }
    }
    unsigned short* Fp = (unsigned short*)(F + (size_t)pid * 672);
    {
        ushort4 o;
        o.x = f2bf(fmaxf(enc0 - 256.f, 0.f)); o.y = f2bf(fmaxf(enc1 - 256.f, 0.f));
        o.z = f2bf(fmaxf(enc2 - 256.f, 0.f)); o.w = f2bf(fmaxf(enc3 - 256.f, 0.f));
        const int co = row * 16 + cg;
        *(ushort4*)(Fp + co) = o;
        *(ushort4*)(Fp + 256 + co) = om;
    }

    // ---- g8 fill: encoded, unconditional shfl + post-masks ----
    {
        const float okU = (r8 > 0) ? 1.f : 0.f;
        const float okD = (r8 < 7) ? 1.f : 0.f;
        const float okL = (c8 > 0) ? 1.f : 0.f;
        const float okR = (c8 < 7) ? 1.f : 0.f;
        const float mUL = okU * okL, mUR = okU * okR, mDL = okD * okL, mDR = okD * okR;
        for (int it = 0; it < 8; ++it) {
            const float nU  = __shfl(enc8, (lane - 8) & 63);
            const float nD  = __shfl(enc8, (lane + 8) & 63);
            const float nL  = __shfl(enc8, (lane - 1) & 63);
            const float nR  = __shfl(enc8, (lane + 1) & 63);
            const float nUL = __shfl(enc8, (lane - 9) & 63);
            const float nUR = __shfl(enc8, (lane - 7) & 63);
            const float nDL = __shfl(enc8, (lane + 7) & 63);
            const float nDR = __shfl(enc8, (lane + 9) & 63);
            float s = (okU * nU + okD * nD) + (okL * nL + okR * nR)
                    + (mUL * nUL + mUR * nUR) + (mDL * nDL + mDR * nDR);
            asm volatile("" :: "v"(s));            // pin to uniform path
            int fill = 0;
            if (enc8 < 256.f) {
                const float Nf = floorf(s * 0.00390625f);
                if (Nf >= 1.f) { enc8 = 256.f + fmaxf(fmaf(Nf, -256.f, s), 0.f) * __builtin_amdgcn_rcpf(Nf); fill = 1; }
            }
            if (!__any(fill)) break;
        }
        Fp[512 + lane] = f2bf(fmaxf(enc8 - 256.f, 0.f));
        Fp[576 + lane] = f2bf(mp8);
    }

    // ---- g4 fill: encoded, 4x4 mirrored across lane groups ----
    {
        const float okU = (r4 > 0) ? 1.f : 0.f;
        const float okD = (r4 < 3) ? 1.f : 0.f;
        const float okL = (c4 > 0) ? 1.f : 0.f;
        const float okR = (c4 < 3) ? 1.f : 0.f;
        const float mUL = okU * okL, mUR = okU * okR, mDL = okD * okL, mDR = okD * okR;
        for (int it = 0; it < 4; ++it) {
            const float nU  = __shfl(enc4, (cell4 - 4) & 63);
            const float nD  = __shfl(enc4, (cell4 + 4) & 63);
            const float nL  = __shfl(enc4, (cell4 - 1) & 63);
            const float nR  = __shfl(enc4, (cell4 + 1) & 63);
            const float nUL = __shfl(enc4, (cell4 - 5) & 63);
            const float nUR = __shfl(enc4, (cell4 - 3) & 63);
            const float nDL = __shfl(enc4, (cell4 + 3) & 63);
            const float nDR = __shfl(enc4, (cell4 + 5) & 63);
            float s = (okU * nU + okD * nD) + (okL * nL + okR * nR)
                    + (mUL * nUL + mUR * nUR) + (mDL * nDL + mDR * nDR);
            asm volatile("" :: "v"(s));            // pin to uniform path
            int fill = 0;
            if (enc4 < 256.f) {
                const float Nf = floorf(s * 0.00390625f);
                if (Nf >= 1.f) { enc4 = 256.f + fmaxf(fmaf(Nf, -256.f, s), 0.f) * __builtin_amdgcn_rcpf(Nf); fill = 1; }
            }
            if (!__any(fill)) break;
        }
        if (lane < 16) {
            Fp[640 + lane] = f2bf(fmaxf(enc4 - 256.f, 0.f));
            Fp[656 + lane] = f2bf(mp4);
        }
        const unsigned long long bal = __ballot(lane < 16 && N4 >= 1.0f);
        if (lane == 0) maskout[pid] = bal ? 1.0f : 0.0f;
    }
}

// -------- GEMM: out[32768][768] = F[32768][672] @ W2[768][672]^T + biasT --------
// 128x128 tile, single-buffered BK=64 (+32-wide tail): R6 structure with half
// the barrier/drain count (21 -> 11 K-steps), 32 MFMA per barrier pair.
// LDS [kcc(8)][row(128)][8] bf16; XCD swizzle for same-tm L2 colocate.
__global__ __launch_bounds__(256) void gemm_kernel(const short* __restrict__ F,
                                                   const short* __restrict__ W2,
                                                   const float* __restrict__ biasT,
                                                   float* __restrict__ out) {
    constexpr int K = 672, N = 768;
    const int bid = blockIdx.x;                    // 1536 = 256 m-tiles x 6 n-tiles
    const int swz = (bid & 7) * 192 + (bid >> 3);  // bijective (1536 % 8 == 0)
    const int tm = swz / 6, tn = swz % 6;
    const int m0 = tm * 128, e0 = tn * 128;
    const int t = threadIdx.x;
    const int wave = t >> 6, lane = t & 63;
    const int wm = wave >> 1, wn = wave & 1;
    const int lg = lane & 15, kc = lane >> 4;

    __shared__ short lds_a[8192];   // [8][128][8] = 16 KB
    __shared__ short lds_b[8192];

    f32x4 acc[4][4];
    const f32x4 zero = {0.f, 0.f, 0.f, 0.f};
    #pragma unroll
    for (int i = 0; i < 4; ++i)
        #pragma unroll
        for (int j = 0; j < 4; ++j) acc[i][j] = zero;

    for (int step = 0; step < 11; ++step) {
        const int kb = step * 64;
        const bool full = (step < 10);             // step 10: 32-wide tail
        __syncthreads();   // previous step's reads done before overwrite
        if (full) {
            #pragma unroll
            for (int c = 0; c < 4; ++c) {
                const int s = wave * 4 + c;        // 16 slots/matrix of 1 KB
                const int kcc = s >> 1, row0 = (s & 1) << 6;
                async_copy16(F  + (size_t)(m0 + row0 + lane) * K + kb + kcc * 8,
                             &lds_a[(kcc * 128 + row0) * 8]);
                async_copy16(W2 + (size_t)(e0 + row0 + lane) * K + kb + kcc * 8,
                             &lds_b[(kcc * 128 + row0) * 8]);
            }
        } else {
            #pragma unroll
            for (int c = 0; c < 2; ++c) {
                const int s = wave * 2 + c;        // 8 slots/matrix
                const int kcc = s >> 1, row0 = (s & 1) << 6;
                async_copy16(F  + (size_t)(m0 + row0 + lane) * K + kb + kcc * 8,
                             &lds_a[(kcc * 128 + row0) * 8]);
                async_copy16(W2 + (size_t)(e0 + row0 + lane) * K + kb + kcc * 8,
                             &lds_b[(kcc * 128 + row0) * 8]);
            }
        }
        __syncthreads();   // vmcnt(0)+lgkm drain: staged data visible

        #pragma unroll
        for (int ks = 0; ks < 2; ++ks) {
            if (ks == 1 && !full) break;
            bf16x8 af[4], bfr[4];
            const int kco = (ks * 4 + kc) * 128;
            #pragma unroll
            for (int i = 0; i < 4; ++i) {
                af[i]  = *(const bf16x8*)&lds_a[(kco + wm * 64 + i * 16 + lg) * 8];
                bfr[i] = *(const bf16x8*)&lds_b[(kco + wn * 64 + i * 16 + lg) * 8];
            }
            #pragma unroll
            for (int i = 0; i < 4; ++i)
                #pragma unroll
                for (int j = 0; j < 4; ++j)
                    acc[i][j] = __builtin_amdgcn_mfma_f32_16x16x32_bf16(af[i], bfr[j], acc[i][j], 0, 0, 0);
        }
    }

    // epilogue: C/D layout col=lane&15, row=(lane>>4)*4+reg (m89-verified)
    const int rbase = (lane >> 4) * 4;
    #pragma unroll
    for (int j = 0; j < 4; ++j) {
        const int e = e0 + wn * 64 + j * 16 + lg;
        const float bs = biasT[e];
        #pragma unroll
        for (int i = 0; i < 4; ++i) {
            const int mr = m0 + wm * 64 + i * 16 + rbase;
            #pragma unroll
            for (int r = 0; r < 4; ++r)
                out[(size_t)(mr + r) * N + e] = acc[i][j][r] + bs;
        }
    }
}

extern "C" void kernel_launch(void* const* d_in, const int* in_sizes, int n_in,
                              void* d_out, int out_size, void* d_ws, size_t ws_size,
                              hipStream_t stream) {
    const float* x  = (const float*)d_in[0];
    const float* w0 = (const float*)d_in[1];
    const float* b0 = (const float*)d_in[2];
    const float* w1 = (const float*)d_in[3];
    const float* b1 = (const float*)d_in[4];
    const float* w2 = (const float*)d_in[5];
    const float* b2 = (const float*)d_in[6];
    float* out = (float*)d_out;

    char* ws = (char*)d_ws;
    __hip_bfloat16* F   = (__hip_bfloat16*)ws;
    __hip_bfloat16* W2  = (__hip_bfloat16*)(ws + 44040192);
    float* biasT        = (float*)(ws + 45072384);
    float* partial      = (float*)(ws + 45075456);
    float* dmin         = (float*)(ws + 45077504);
    float* maskout      = out + 25165824;   // feat is 32*1024*768

    min_partial_kernel<<<512, 256, 0, stream>>>(x, partial);
    min_final_kernel<<<1, 64, 0, stream>>>(partial, dmin);
    prep_kernel<<<2016, 256, 0, stream>>>(w0, b0, w1, b1, w2, b2, W2, biasT);
    patch_kernel<<<8192, 256, 0, stream>>>(x, dmin, F, maskout);
    gemm_kernel<<<1536, 256, 0, stream>>>((const short*)F, (const short*)W2, biasT, out);
}